// Round 8
// baseline (336.100 us; speedup 1.0000x reference)
//
#include <hip/hip_runtime.h>

typedef short short8 __attribute__((ext_vector_type(8)));
typedef float f32x4 __attribute__((ext_vector_type(4)));
typedef float f32x16 __attribute__((ext_vector_type(16)));
typedef unsigned short ushort4v __attribute__((ext_vector_type(4)));
typedef unsigned int uint4v __attribute__((ext_vector_type(4)));
typedef unsigned long long u64;

#define N_B   4
#define S_LEN 2048
#define EMB   512
#define HD    64
#define NHB   32
// 1/sqrt(512) * log2(e): p = exp2(s), native v_exp_f32
#define QSCALE 0.063758714f
#define EXP2F(x) __builtin_amdgcn_exp2f(x)

__device__ unsigned short g_Wqb[64*64];
__device__ unsigned short g_Wkb[64*64];
__device__ unsigned short g_Wvb[64*64];
__device__ unsigned short g_Wob[512*512];
__device__ unsigned short g_Qp[NHB*S_LEN*HD];   // [nh][s][d] (pre-scaled)
__device__ unsigned short g_Kp[NHB*S_LEN*HD];   // [nh][s][d]
__device__ unsigned short g_Vt[NHB*HD*S_LEN];   // [nh][d][s]
__device__ unsigned short g_AO[N_B*S_LEN*EMB];  // attention out bf16
__device__ u64            g_Mb[N_B*32*S_LEN];   // packed mask [n][t][q]

__device__ __forceinline__ unsigned short f2bf(float f) {
  unsigned u = __float_as_uint(f);
  u = u + 0x7fffu + ((u >> 16) & 1u);
  return (unsigned short)(u >> 16);
}
__device__ __forceinline__ unsigned cvt_pk_bf16(float a, float b) {
  unsigned r;
  asm("v_cvt_pk_bf16_f32 %0, %1, %2" : "=v"(r) : "v"(a), "v"(b));
  return r;   // lo = bf16(a), hi = bf16(b)
}

// ---------------- prep: weights f32->bf16 + mask bit-pack ---------------
__global__ __launch_bounds__(256) void k0_prep(const float* __restrict__ Wq,
                                               const float* __restrict__ Wk,
                                               const float* __restrict__ Wv,
                                               const float* __restrict__ Wo,
                                               const int* __restrict__ mask) {
  const int b = blockIdx.x;
  if (b < 1072) {
    int idx = b * 256 + threadIdx.x;            // 274432 total
    if (idx < 4096)        g_Wqb[idx]         = f2bf(Wq[idx] * QSCALE);
    else if (idx < 8192)   g_Wkb[idx - 4096]  = f2bf(Wk[idx - 4096]);
    else if (idx < 12288)  g_Wvb[idx - 8192]  = f2bf(Wv[idx - 8192]);
    else                   g_Wob[idx - 12288] = f2bf(Wo[idx - 12288]);
  } else {
    int wid = (b - 1072) * 4 + (threadIdx.x >> 6);   // 8192 waves = (n,q)
    int lane = threadIdx.x & 63;
    int n = wid >> 11, q = wid & 2047;
    const int* base = mask + ((size_t)(n * 2048 + q) << 11);
    u64* dst = g_Mb + (size_t)n * 32 * S_LEN + q;
#pragma unroll 4
    for (int j = 0; j < 32; ++j) {
      int mk = base[j * 64 + lane];
      u64 bits = __ballot(mk != 0);
      if (lane == 0) dst[(size_t)j * S_LEN] = bits;
    }
  }
}

// ---------------- k1: QKV projections, all 8 heads per block ------------
// W shared across heads: fragments loaded once; X rows read ONCE grid-wide.
__global__ __launch_bounds__(256) void k1_proj(const float* __restrict__ q_in,
                                               const float* __restrict__ k_in,
                                               const float* __restrict__ v_in) {
  __shared__ unsigned short VtL[64][72];
  const int tid = threadIdx.x;
  const int w = tid >> 6, lane = tid & 63, g = lane >> 4, c = lane & 15;
  const int s0 = blockIdx.x * 64;
  const int n = blockIdx.y;
  const int which = blockIdx.z;                 // 0=q 1=k 2=v
  const float* src = which == 0 ? q_in : (which == 1 ? k_in : v_in);
  const unsigned short* Wb = which == 0 ? g_Wqb : (which == 1 ? g_Wkb : g_Wvb);

  const int srow = s0 + w * 16 + c;
  const float* rowp = src + ((size_t)n * S_LEN + srow) * EMB;

  short8 wf[2][4];
#pragma unroll
  for (int ks = 0; ks < 2; ++ks)
#pragma unroll
    for (int dt = 0; dt < 4; ++dt)
      wf[ks][dt] = *(const short8*)(Wb + (dt * 16 + c) * HD + ks * 32 + g * 8);

  for (int hd = 0; hd < 8; ++hd) {
    short8 xb[2];
#pragma unroll
    for (int ks = 0; ks < 2; ++ks) {
      const float* ap = rowp + hd * HD + ks * 32 + g * 8;
      f32x4 x0 = *(const f32x4*)ap;
      f32x4 x1 = *(const f32x4*)(ap + 4);
      short8 tt;
      tt[0] = (short)f2bf(x0[0]); tt[1] = (short)f2bf(x0[1]);
      tt[2] = (short)f2bf(x0[2]); tt[3] = (short)f2bf(x0[3]);
      tt[4] = (short)f2bf(x1[0]); tt[5] = (short)f2bf(x1[1]);
      tt[6] = (short)f2bf(x1[2]); tt[7] = (short)f2bf(x1[3]);
      xb[ks] = tt;
    }
    f32x4 acc[4];
#pragma unroll
    for (int dt = 0; dt < 4; ++dt) { acc[dt][0]=0.f; acc[dt][1]=0.f; acc[dt][2]=0.f; acc[dt][3]=0.f; }
#pragma unroll
    for (int ks = 0; ks < 2; ++ks)
#pragma unroll
      for (int dt = 0; dt < 4; ++dt)
        acc[dt] = __builtin_amdgcn_mfma_f32_16x16x32_bf16(wf[ks][dt], xb[ks], acc[dt], 0, 0, 0);

    const int nh = n * 8 + hd;
    if (which < 2) {
      unsigned short* dst = which == 0 ? g_Qp : g_Kp;
#pragma unroll
      for (int dt = 0; dt < 4; ++dt) {
        ushort4v u;
        u[0] = f2bf(acc[dt][0]); u[1] = f2bf(acc[dt][1]);
        u[2] = f2bf(acc[dt][2]); u[3] = f2bf(acc[dt][3]);
        *(ushort4v*)(dst + ((size_t)nh * S_LEN + srow) * HD + dt * 16 + 4 * g) = u;
      }
    } else {
      if (hd) __syncthreads();
#pragma unroll
      for (int dt = 0; dt < 4; ++dt)
#pragma unroll
        for (int r = 0; r < 4; ++r)
          VtL[dt * 16 + 4 * g + r][w * 16 + c] = f2bf(acc[dt][r]);
      __syncthreads();
#pragma unroll
      for (int rep = 0; rep < 2; ++rep) {
        int cid = tid + rep * 256;
        int row = cid >> 3, ch = cid & 7;
        short8 v = *(const short8*)(&VtL[row][ch * 8]);
        *(short8*)(g_Vt + ((size_t)nh * HD + row) * S_LEN + s0 + ch * 8) = v;
      }
    }
  }
}

// ---------------- k2: flash attention, 32x32 swapped MFMA ----------------
// 8 waves: waves 0-3 kv[0,1024), waves 4-7 kv[1024,2048), same 128 q-rows.
// S^T = mfma(K,Q): lane owns full kv-slice of ONE q (col=lane&31).
// Denominator: register sum + shfl_xor(32). P exchange: shfl, no LDS P.
__global__ __launch_bounds__(512, 4) void k2_attn() {
  __shared__ alignas(16) unsigned short Kl[2][2][64][64];  // [half][buf][kv][d]
  __shared__ alignas(16) unsigned short Vl[2][2][64][64];  // [half][buf][d][kv]
  const int tid = threadIdx.x;
  const int w = tid >> 6, lane = tid & 63;
  const int q32 = lane & 31, hh = lane >> 5;
  const int half = w >> 2;
  const int q0 = blockIdx.x * 128;
  const int nh = blockIdx.y, n = nh >> 3, h = nh & 7;
  const int qrow = q0 + (w & 3) * 32 + q32;

  // Q fragments: B-operand (col=q), k=(l>>5)*8+j per 16-kstep
  short8 qf[4];
#pragma unroll
  for (int ks = 0; ks < 4; ++ks)
    qf[ks] = *(const short8*)(g_Qp + ((size_t)nh * S_LEN + qrow) * HD + ks * 16 + hh * 8);

  // staging (per half: 256 threads, 64 rows x 8 chunks16, 2 chunks/thread)
  const int th = tid & 255;
  const int srow = th >> 2;
  const int scp = (th & 3) * 2;
  const unsigned short* ksrc = g_Kp + ((size_t)nh * S_LEN + half * 1024 + srow) * HD + scp * 8;
  const unsigned short* vsrc = g_Vt + ((size_t)nh * HD + srow) * S_LEN + half * 1024 + scp * 8;
  const int kd0 = ((scp) ^ (srow & 7)) * 8;
  const int kd1 = ((scp + 1) ^ (srow & 7)) * 8;
  const u64* mptr = g_Mb + ((size_t)n * 32 + half * 16) * S_LEN + qrow;

  f32x16 O0, O1;
#pragma unroll
  for (int i = 0; i < 16; ++i) { O0[i] = 0.f; O1[i] = 0.f; }
  float ld = 0.f;

  // prologue: tile 0 of this half
  short8 ka0 = *(const short8*)(ksrc);
  short8 ka1 = *(const short8*)(ksrc + 8);
  short8 va0 = *(const short8*)(vsrc);
  short8 va1 = *(const short8*)(vsrc + 8);
  u64 mcur = mptr[0];
  *(short8*)(&Kl[half][0][srow][kd0]) = ka0;
  *(short8*)(&Kl[half][0][srow][kd1]) = ka1;
  *(short8*)(&Vl[half][0][srow][kd0]) = va0;
  *(short8*)(&Vl[half][0][srow][kd1]) = va1;
  __syncthreads();

  for (int tl = 0; tl < 16; ++tl) {
    const int cur = tl & 1;
    u64 mnext = 0;
    if (tl < 15) {
      ka0 = *(const short8*)(ksrc + (size_t)(tl + 1) * 4096);
      ka1 = *(const short8*)(ksrc + (size_t)(tl + 1) * 4096 + 8);
      va0 = *(const short8*)(vsrc + (tl + 1) * 64);
      va1 = *(const short8*)(vsrc + (tl + 1) * 64 + 8);
      mnext = mptr[(size_t)(tl + 1) * S_LEN];
    }

    // QK^T (S^T) + softmax, subtile-at-a-time to cap register pressure
    unsigned cL[16];
    float psum = 0.f;
#pragma unroll
    for (int st = 0; st < 2; ++st) {
      f32x16 sa;
#pragma unroll
      for (int i = 0; i < 16; ++i) sa[i] = 0.f;
      const int arow = st * 32 + q32;
#pragma unroll
      for (int ks = 0; ks < 4; ++ks) {
        short8 ka = *(const short8*)(&Kl[half][cur][arow][((2 * ks + hh) ^ (arow & 7)) * 8]);
        sa = __builtin_amdgcn_mfma_f32_32x32x16_bf16(ka, qf[ks], sa, 0, 0, 0);
      }
      // lane's 16 values: kv = st*32 + 8*j2 + 4*hh + i  (reg = 4*j2+i)
      unsigned mw = st ? (unsigned)(mcur >> 32) : (unsigned)mcur;
      const int shb = 4 * hh;
#pragma unroll
      for (int j2 = 0; j2 < 4; ++j2) {
        float p0 = ((mw >> (8 * j2 + shb + 0)) & 1u) ? EXP2F(sa[4 * j2 + 0]) : 0.f;
        float p1 = ((mw >> (8 * j2 + shb + 1)) & 1u) ? EXP2F(sa[4 * j2 + 1]) : 0.f;
        float p2 = ((mw >> (8 * j2 + shb + 2)) & 1u) ? EXP2F(sa[4 * j2 + 2]) : 0.f;
        float p3 = ((mw >> (8 * j2 + shb + 3)) & 1u) ? EXP2F(sa[4 * j2 + 3]) : 0.f;
        psum += (p0 + p1) + (p2 + p3);
        cL[st * 8 + 2 * j2]     = cvt_pk_bf16(p0, p1);
        cL[st * 8 + 2 * j2 + 1] = cvt_pk_bf16(p2, p3);
      }
    }
    ld += psum + __shfl_xor(psum, 32);

    // PV: A-frag kv-chunk JJ=2*ks+hh; exchange halves lane<->lane^32
#pragma unroll
    for (int ks = 0; ks < 4; ++ks) {
      unsigned s0v = __shfl_xor(cL[4 * ks + 0], 32);
      unsigned s1v = __shfl_xor(cL[4 * ks + 1], 32);
      unsigned s2v = __shfl_xor(cL[4 * ks + 2], 32);
      unsigned s3v = __shfl_xor(cL[4 * ks + 3], 32);
      uint4v fv;
      fv[0] = hh ? s2v : cL[4 * ks + 0];
      fv[1] = hh ? s3v : cL[4 * ks + 1];
      fv[2] = hh ? cL[4 * ks + 2] : s0v;
      fv[3] = hh ? cL[4 * ks + 3] : s1v;
      short8 pa = __builtin_bit_cast(short8, fv);
      const int vr0 = q32;
      short8 vb0 = *(const short8*)(&Vl[half][cur][vr0][((2 * ks + hh) ^ (vr0 & 7)) * 8]);
      O0 = __builtin_amdgcn_mfma_f32_32x32x16_bf16(pa, vb0, O0, 0, 0, 0);
      const int vr1 = 32 + q32;
      short8 vb1 = *(const short8*)(&Vl[half][cur][vr1][((2 * ks + hh) ^ (vr1 & 7)) * 8]);
      O1 = __builtin_amdgcn_mfma_f32_32x32x16_bf16(pa, vb1, O1, 0, 0, 0);
    }

    if (tl < 15) {
      *(short8*)(&Kl[half][cur ^ 1][srow][kd0]) = ka0;
      *(short8*)(&Kl[half][cur ^ 1][srow][kd1]) = ka1;
      *(short8*)(&Vl[half][cur ^ 1][srow][kd0]) = va0;
      *(short8*)(&Vl[half][cur ^ 1][srow][kd1]) = va1;
      mcur = mnext;
    }
    __syncthreads();
  }

  // merge halves through LDS (reuse tile space), then normalize+store
  float* Olds = (float*)&Kl[0][0][0][0];   // 128 x 64 f32 = 32KB
  float* Lsum = (float*)&Vl[0][0][0][0];   // 128 f32
  const int qb = (w & 3) * 32;
  if (half == 0) {
#pragma unroll
    for (int r = 0; r < 16; ++r) {
      int qq = qb + (r & 3) + 8 * (r >> 2) + 4 * hh;
      Olds[qq * 64 + q32]      = O0[r];
      Olds[qq * 64 + 32 + q32] = O1[r];
    }
    if (hh == 0) Lsum[qb + q32] = ld;
  }
  __syncthreads();
  if (half == 1) {
#pragma unroll
    for (int r = 0; r < 16; ++r) {
      int qq = qb + (r & 3) + 8 * (r >> 2) + 4 * hh;
      Olds[qq * 64 + q32]      += O0[r];
      Olds[qq * 64 + 32 + q32] += O1[r];
    }
    if (hh == 0) Lsum[qb + q32] += ld;
  }
  __syncthreads();
  {
    const int rr = tid >> 2;
    const int dch = (tid & 3) * 16;
    float l = Lsum[rr];
    float inv = l > 0.f ? 1.f / l : 0.f;
    const float* op = &Olds[rr * 64 + dch];
    unsigned pk[8];
#pragma unroll
    for (int j = 0; j < 8; ++j)
      pk[j] = cvt_pk_bf16(op[2 * j] * inv, op[2 * j + 1] * inv);
    uint4v lo4 = {pk[0], pk[1], pk[2], pk[3]};
    uint4v hi4 = {pk[4], pk[5], pk[6], pk[7]};
    unsigned short* dst = g_AO + ((size_t)n * S_LEN + q0 + rr) * EMB + h * HD + dch;
    *(short8*)(dst)     = __builtin_bit_cast(short8, lo4);
    *(short8*)(dst + 8) = __builtin_bit_cast(short8, hi4);
  }
}

// ---------------- k3: output projection (8192x512x512) + bias ------------
__global__ __launch_bounds__(256) void k3_oproj(const float* __restrict__ bo,
                                                float* __restrict__ out) {
  const int tid = threadIdx.x;
  const int w = tid >> 6, lane = tid & 63, g = lane >> 4, c = lane & 15;
  const int m0 = blockIdx.x * 64;
  const int n0 = blockIdx.y * 64;

  f32x4 acc[4];
#pragma unroll
  for (int ct = 0; ct < 4; ++ct) { acc[ct][0]=0.f; acc[ct][1]=0.f; acc[ct][2]=0.f; acc[ct][3]=0.f; }

  for (int ks = 0; ks < 16; ++ks) {
    short8 a = *(const short8*)(g_AO + ((size_t)(m0 + w * 16 + c)) * EMB + ks * 32 + g * 8);
#pragma unroll
    for (int ct = 0; ct < 4; ++ct) {
      short8 b = *(const short8*)(g_Wob + (size_t)(n0 + ct * 16 + c) * EMB + ks * 32 + g * 8);
      acc[ct] = __builtin_amdgcn_mfma_f32_16x16x32_bf16(a, b, acc[ct], 0, 0, 0);
    }
  }

#pragma unroll
  for (int ct = 0; ct < 4; ++ct) {
    int col = n0 + ct * 16 + c;
    float bias = bo[col];
#pragma unroll
    for (int r = 0; r < 4; ++r) {
      int row = m0 + w * 16 + 4 * g + r;
      out[(size_t)row * EMB + col] = acc[ct][r] + bias;
    }
  }
}

extern "C" void kernel_launch(void* const* d_in, const int* in_sizes, int n_in,
                              void* d_out, int out_size, void* d_ws, size_t ws_size,
                              hipStream_t stream) {
  const float* value = (const float*)d_in[0];
  const float* key   = (const float*)d_in[1];
  const float* query = (const float*)d_in[2];
  const int*   mask  = (const int*)d_in[3];
  const float* Wq    = (const float*)d_in[4];
  const float* Wk    = (const float*)d_in[5];
  const float* Wv    = (const float*)d_in[6];
  const float* Wo    = (const float*)d_in[7];
  const float* bo    = (const float*)d_in[8];
  float* out = (float*)d_out;

  k0_prep<<<3120, 256, 0, stream>>>(Wq, Wk, Wv, Wo, mask);
  k1_proj<<<dim3(32, 4, 3), 256, 0, stream>>>(query, key, value);
  k2_attn<<<dim3(16, 32), 512, 0, stream>>>();
  k3_oproj<<<dim3(128, 8), 256, 0, stream>>>(bo, out);
}

// Round 9
// 270.572 us; speedup vs baseline: 1.2422x; 1.2422x over previous
//
#include <hip/hip_runtime.h>

typedef short short8 __attribute__((ext_vector_type(8)));
typedef float f32x4 __attribute__((ext_vector_type(4)));
typedef unsigned short ushort4v __attribute__((ext_vector_type(4)));
typedef unsigned int uint4v __attribute__((ext_vector_type(4)));
typedef unsigned long long u64;
typedef u64 u64x2 __attribute__((ext_vector_type(2)));

#define N_B   4
#define S_LEN 2048
#define EMB   512
#define HD    64
#define NHB   32
// 1/sqrt(512) * log2(e): p = exp2(s), native v_exp_f32
#define QSCALE 0.063758714f
#define EXP2F(x) __builtin_amdgcn_exp2f(x)

__device__ unsigned short g_Wqb[64*64];
__device__ unsigned short g_Wkb[64*64];
__device__ unsigned short g_Wvb[64*64];
__device__ unsigned short g_Wob[512*512];
__device__ unsigned short g_Qp[NHB*S_LEN*HD];   // [nh][s][d] (pre-scaled)
__device__ unsigned short g_Kp[NHB*S_LEN*HD];   // [nh][s][d]
__device__ unsigned short g_Vt[NHB*HD*S_LEN];   // [nh][d][s]
__device__ unsigned short g_AO[N_B*S_LEN*EMB];  // attention out bf16
__device__ u64            g_Mb[N_B*32*S_LEN];   // packed mask [n][t][q]

__device__ __forceinline__ unsigned short f2bf(float f) {
  unsigned u = __float_as_uint(f);
  u = u + 0x7fffu + ((u >> 16) & 1u);
  return (unsigned short)(u >> 16);
}
__device__ __forceinline__ unsigned cvt_pk_bf16(float a, float b) {
  unsigned r;
  asm("v_cvt_pk_bf16_f32 %0, %1, %2" : "=v"(r) : "v"(a), "v"(b));
  return r;   // lo = bf16(a), hi = bf16(b)
}

// ---------------- prep: weights f32->bf16 + mask bit-pack ---------------
__global__ __launch_bounds__(256) void k0_prep(const float* __restrict__ Wq,
                                               const float* __restrict__ Wk,
                                               const float* __restrict__ Wv,
                                               const float* __restrict__ Wo,
                                               const int* __restrict__ mask) {
  const int b = blockIdx.x;
  if (b < 1072) {
    int idx = b * 256 + threadIdx.x;            // 274432 total
    if (idx < 4096)        g_Wqb[idx]         = f2bf(Wq[idx] * QSCALE);
    else if (idx < 8192)   g_Wkb[idx - 4096]  = f2bf(Wk[idx - 4096]);
    else if (idx < 12288)  g_Wvb[idx - 8192]  = f2bf(Wv[idx - 8192]);
    else                   g_Wob[idx - 12288] = f2bf(Wo[idx - 12288]);
  } else {
    int wid = (b - 1072) * 4 + (threadIdx.x >> 6);   // 8192 waves = (n,q)
    int lane = threadIdx.x & 63;
    int n = wid >> 11, q = wid & 2047;
    const int* base = mask + ((size_t)(n * 2048 + q) << 11);
    u64* dst = g_Mb + (size_t)n * 32 * S_LEN + q;
#pragma unroll 4
    for (int j = 0; j < 32; ++j) {
      int mk = base[j * 64 + lane];
      u64 bits = __ballot(mk != 0);
      if (lane == 0) dst[(size_t)j * S_LEN] = bits;
    }
  }
}

// ---------------- k1: QKV projections, all 8 heads per block ------------
// W shared across heads: fragments loaded once; X rows read ONCE grid-wide.
__global__ __launch_bounds__(256) void k1_proj(const float* __restrict__ q_in,
                                               const float* __restrict__ k_in,
                                               const float* __restrict__ v_in) {
  __shared__ unsigned short VtL[64][72];
  const int tid = threadIdx.x;
  const int w = tid >> 6, lane = tid & 63, g = lane >> 4, c = lane & 15;
  const int s0 = blockIdx.x * 64;
  const int n = blockIdx.y;
  const int which = blockIdx.z;                 // 0=q 1=k 2=v
  const float* src = which == 0 ? q_in : (which == 1 ? k_in : v_in);
  const unsigned short* Wb = which == 0 ? g_Wqb : (which == 1 ? g_Wkb : g_Wvb);

  const int srow = s0 + w * 16 + c;
  const float* rowp = src + ((size_t)n * S_LEN + srow) * EMB;

  short8 wf[2][4];
#pragma unroll
  for (int ks = 0; ks < 2; ++ks)
#pragma unroll
    for (int dt = 0; dt < 4; ++dt)
      wf[ks][dt] = *(const short8*)(Wb + (dt * 16 + c) * HD + ks * 32 + g * 8);

  for (int hd = 0; hd < 8; ++hd) {
    short8 xb[2];
#pragma unroll
    for (int ks = 0; ks < 2; ++ks) {
      const float* ap = rowp + hd * HD + ks * 32 + g * 8;
      f32x4 x0 = *(const f32x4*)ap;
      f32x4 x1 = *(const f32x4*)(ap + 4);
      short8 tt;
      tt[0] = (short)f2bf(x0[0]); tt[1] = (short)f2bf(x0[1]);
      tt[2] = (short)f2bf(x0[2]); tt[3] = (short)f2bf(x0[3]);
      tt[4] = (short)f2bf(x1[0]); tt[5] = (short)f2bf(x1[1]);
      tt[6] = (short)f2bf(x1[2]); tt[7] = (short)f2bf(x1[3]);
      xb[ks] = tt;
    }
    f32x4 acc[4];
#pragma unroll
    for (int dt = 0; dt < 4; ++dt) { acc[dt][0]=0.f; acc[dt][1]=0.f; acc[dt][2]=0.f; acc[dt][3]=0.f; }
#pragma unroll
    for (int ks = 0; ks < 2; ++ks)
#pragma unroll
      for (int dt = 0; dt < 4; ++dt)
        acc[dt] = __builtin_amdgcn_mfma_f32_16x16x32_bf16(wf[ks][dt], xb[ks], acc[dt], 0, 0, 0);

    const int nh = n * 8 + hd;
    if (which < 2) {
      unsigned short* dst = which == 0 ? g_Qp : g_Kp;
#pragma unroll
      for (int dt = 0; dt < 4; ++dt) {
        ushort4v u;
        u[0] = f2bf(acc[dt][0]); u[1] = f2bf(acc[dt][1]);
        u[2] = f2bf(acc[dt][2]); u[3] = f2bf(acc[dt][3]);
        *(ushort4v*)(dst + ((size_t)nh * S_LEN + srow) * HD + dt * 16 + 4 * g) = u;
      }
    } else {
      if (hd) __syncthreads();
#pragma unroll
      for (int dt = 0; dt < 4; ++dt)
#pragma unroll
        for (int r = 0; r < 4; ++r)
          VtL[dt * 16 + 4 * g + r][w * 16 + c] = f2bf(acc[dt][r]);
      __syncthreads();
#pragma unroll
      for (int rep = 0; rep < 2; ++rep) {
        int cid = tid + rep * 256;
        int row = cid >> 3, ch = cid & 7;
        short8 v = *(const short8*)(&VtL[row][ch * 8]);
        *(short8*)(g_Vt + ((size_t)nh * HD + row) * S_LEN + s0 + ch * 8) = v;
      }
    }
  }
}

// ---------------- k2: flash attention (round-7 core + XCD remap) ---------
// 8 waves x 16 q-rows = 128 q/block; dbuf swizzled LDS, ONE barrier/tile.
// Row-sums via 16 all-ones V rows (dt=4 MFMA tile) -> O5; out = O4/O5.
// Block remap: XCD k owns heads 4k..4k+3 -> K/V panels stay L2-resident.
__global__ __launch_bounds__(512) void k2_attn() {
  __shared__ unsigned short Kl[2][64][64];   // [buf][kv][d], chunk^=(row&7)
  __shared__ unsigned short Vl[2][80][64];   // [buf][d][kv]; rows 64..79 = 1.0
  __shared__ unsigned short Pl[8][16][64];   // per-wave P [q][kv], swizzled
  const int tid = threadIdx.x;
  const int w = tid >> 6, lane = tid & 63, g = lane >> 4, c = lane & 15;
  // XCD-aware decode: L%8 = XCD; each XCD gets 4 heads x 16 q-blocks
  const int L = blockIdx.x;
  const int m = L >> 3;
  const int nh = (L & 7) * 4 + (m >> 4);
  const int q0 = (m & 15) * 128;
  const int n = nh >> 3;

  // Q fragments (16 rows per wave)
  short8 aq[2];
#pragma unroll
  for (int ks = 0; ks < 2; ++ks)
    aq[ks] = *(const short8*)(g_Qp + ((size_t)nh * S_LEN + q0 + w * 16 + c) * HD + ks * 32 + g * 8);

  // staging: 512 threads cover 64 rows x 8 chunks (16B each)
  const int strow = tid >> 3, schunk = tid & 7;
  const int sdst = (schunk ^ (strow & 7)) * 8;
  const unsigned short* ksrc = g_Kp + ((size_t)nh * S_LEN + strow) * HD + schunk * 8;
  const unsigned short* vsrc = g_Vt + ((size_t)nh * HD + strow) * S_LEN + schunk * 8;
  const u64* mbase = g_Mb + ((size_t)n * 32) * S_LEN + q0 + w * 16 + 4 * g;

  // ones rows (both buffers): [2][16][64] u16 = 2048; 512 thr x 4
  {
    int flat = tid * 4;
    int b = flat >> 10, rem = flat & 1023, rr = rem >> 6, cc = rem & 63;
    ushort4v ones4 = {0x3f80, 0x3f80, 0x3f80, 0x3f80};
    *(ushort4v*)(&Vl[b][64 + rr][cc]) = ones4;
  }

  f32x4 O4[4], O5;
#pragma unroll
  for (int dt = 0; dt < 4; ++dt) { O4[dt][0]=0.f; O4[dt][1]=0.f; O4[dt][2]=0.f; O4[dt][3]=0.f; }
  O5[0]=0.f; O5[1]=0.f; O5[2]=0.f; O5[3]=0.f;

  // prologue: tile 0
  short8 kst = *(const short8*)(ksrc);
  short8 vst = *(const short8*)(vsrc);
  u64x2 mA = *(const u64x2*)(mbase);
  u64x2 mB = *(const u64x2*)(mbase + 2);
  *(short8*)(&Kl[0][strow][sdst]) = kst;
  *(short8*)(&Vl[0][strow][sdst]) = vst;
  __syncthreads();

  for (int t = 0; t < 32; ++t) {
    const int cur = t & 1;
    u64x2 mAn, mBn;
    if (t < 31) {                       // prefetch t+1 (hidden under compute)
      kst = *(const short8*)(ksrc + (size_t)(t + 1) * 64 * HD);
      vst = *(const short8*)(vsrc + (t + 1) * 64);
      mAn = *(const u64x2*)(mbase + (size_t)(t + 1) * S_LEN);
      mBn = *(const u64x2*)(mbase + (size_t)(t + 1) * S_LEN + 2);
    }

    // S = Q K^T  (16 q-rows x 64 kv per wave), pre-scaled by QSCALE
    f32x4 sa[4];
#pragma unroll
    for (int ct = 0; ct < 4; ++ct) { sa[ct][0]=0.f; sa[ct][1]=0.f; sa[ct][2]=0.f; sa[ct][3]=0.f; }
#pragma unroll
    for (int ks = 0; ks < 2; ++ks)
#pragma unroll
      for (int ct = 0; ct < 4; ++ct) {
        short8 bk = *(const short8*)(&Kl[cur][ct * 16 + c][((g + 4 * ks) ^ (c & 7)) * 8]);
        sa[ct] = __builtin_amdgcn_mfma_f32_16x16x32_bf16(aq[ks], bk, sa[ct], 0, 0, 0);
      }

    // P = mask ? exp2(s) : 0   (no max subtraction: |s| <~ 1)
    unsigned lo0 = (unsigned)mA[0], hi0 = (unsigned)(mA[0] >> 32);
    unsigned lo1 = (unsigned)mA[1], hi1 = (unsigned)(mA[1] >> 32);
    unsigned lo2 = (unsigned)mB[0], hi2 = (unsigned)(mB[0] >> 32);
    unsigned lo3 = (unsigned)mB[1], hi3 = (unsigned)(mB[1] >> 32);
#pragma unroll
    for (int ct = 0; ct < 4; ++ct) {
      const int sh = (ct & 1) * 16 + c;
      float p0 = ((((ct & 2) ? hi0 : lo0) >> sh) & 1u) ? EXP2F(sa[ct][0]) : 0.f;
      float p1 = ((((ct & 2) ? hi1 : lo1) >> sh) & 1u) ? EXP2F(sa[ct][1]) : 0.f;
      float p2 = ((((ct & 2) ? hi2 : lo2) >> sh) & 1u) ? EXP2F(sa[ct][2]) : 0.f;
      float p3 = ((((ct & 2) ? hi3 : lo3) >> sh) & 1u) ? EXP2F(sa[ct][3]) : 0.f;
      unsigned pk01 = cvt_pk_bf16(p0, p1);
      unsigned pk23 = cvt_pk_bf16(p2, p3);
      const int col = ct * 16 + c;
      const int chs = ((col >> 3) << 3);
#pragma unroll
      for (int r = 0; r < 4; ++r) {
        int prow = 4 * g + r;
        unsigned pk = (r < 2) ? pk01 : pk23;
        unsigned short v = (r & 1) ? (unsigned short)(pk >> 16) : (unsigned short)pk;
        Pl[w][prow][(chs ^ ((prow & 7) << 3)) | (col & 7)] = v;
      }
    }

    // O += P V  (dt=0..3: output dims; dt=4: ones rows -> row-sum into O5)
#pragma unroll
    for (int ks = 0; ks < 2; ++ks) {
      short8 pa = *(const short8*)(&Pl[w][c][((g + 4 * ks) ^ (c & 7)) * 8]);
#pragma unroll
      for (int dt = 0; dt < 5; ++dt) {
        short8 bv = *(const short8*)(&Vl[cur][dt * 16 + c][((g + 4 * ks) ^ (c & 7)) * 8]);
        if (dt < 4)
          O4[dt] = __builtin_amdgcn_mfma_f32_16x16x32_bf16(pa, bv, O4[dt], 0, 0, 0);
        else
          O5 = __builtin_amdgcn_mfma_f32_16x16x32_bf16(pa, bv, O5, 0, 0, 0);
      }
    }

    if (t < 31) {
      *(short8*)(&Kl[cur ^ 1][strow][sdst]) = kst;
      *(short8*)(&Vl[cur ^ 1][strow][sdst]) = vst;
      mA = mAn; mB = mBn;
      __syncthreads();                   // single barrier per tile
    }
  }

  // epilogue: out = O4 / O5
  const int h = nh & 7;
#pragma unroll
  for (int r = 0; r < 4; ++r) {
    float inv = O5[r] > 0.f ? 1.f / O5[r] : 0.f;
    int qr = q0 + w * 16 + 4 * g + r;
#pragma unroll
    for (int dt = 0; dt < 4; ++dt)
      g_AO[((size_t)n * S_LEN + qr) * EMB + h * HD + dt * 16 + c] = f2bf(O4[dt][r] * inv);
  }
}

// ---------------- k3: output projection (8192x512x512) + bias ------------
__global__ __launch_bounds__(256) void k3_oproj(const float* __restrict__ bo,
                                                float* __restrict__ out) {
  const int tid = threadIdx.x;
  const int w = tid >> 6, lane = tid & 63, g = lane >> 4, c = lane & 15;
  const int m0 = blockIdx.x * 64;
  const int n0 = blockIdx.y * 64;

  f32x4 acc[4];
#pragma unroll
  for (int ct = 0; ct < 4; ++ct) { acc[ct][0]=0.f; acc[ct][1]=0.f; acc[ct][2]=0.f; acc[ct][3]=0.f; }

  for (int ks = 0; ks < 16; ++ks) {
    short8 a = *(const short8*)(g_AO + ((size_t)(m0 + w * 16 + c)) * EMB + ks * 32 + g * 8);
#pragma unroll
    for (int ct = 0; ct < 4; ++ct) {
      short8 b = *(const short8*)(g_Wob + (size_t)(n0 + ct * 16 + c) * EMB + ks * 32 + g * 8);
      acc[ct] = __builtin_amdgcn_mfma_f32_16x16x32_bf16(a, b, acc[ct], 0, 0, 0);
    }
  }

#pragma unroll
  for (int ct = 0; ct < 4; ++ct) {
    int col = n0 + ct * 16 + c;
    float bias = bo[col];
#pragma unroll
    for (int r = 0; r < 4; ++r) {
      int row = m0 + w * 16 + 4 * g + r;
      out[(size_t)row * EMB + col] = acc[ct][r] + bias;
    }
  }
}

extern "C" void kernel_launch(void* const* d_in, const int* in_sizes, int n_in,
                              void* d_out, int out_size, void* d_ws, size_t ws_size,
                              hipStream_t stream) {
  const float* value = (const float*)d_in[0];
  const float* key   = (const float*)d_in[1];
  const float* query = (const float*)d_in[2];
  const int*   mask  = (const int*)d_in[3];
  const float* Wq    = (const float*)d_in[4];
  const float* Wk    = (const float*)d_in[5];
  const float* Wv    = (const float*)d_in[6];
  const float* Wo    = (const float*)d_in[7];
  const float* bo    = (const float*)d_in[8];
  float* out = (float*)d_out;

  k0_prep<<<3120, 256, 0, stream>>>(Wq, Wk, Wv, Wo, mask);
  k1_proj<<<dim3(32, 4, 3), 256, 0, stream>>>(query, key, value);
  k2_attn<<<512, 512, 0, stream>>>();
  k3_oproj<<<dim3(128, 8), 256, 0, stream>>>(bo, out);
}